// Round 6
// baseline (2179.127 us; speedup 1.0000x reference)
//
#include <hip/hip_runtime.h>
#include <hip/hip_fp16.h>
#include <cstdint>

#define T_DIM 1024
#define B_DIM 256
#define D_DIM 128
#define H_DIM 128
#define G_DIM 512

typedef _Float16 f16x8 __attribute__((ext_vector_type(8)));
typedef float    f32x4 __attribute__((ext_vector_type(4)));

__device__ __forceinline__ float fastrcp(float x) {
#if __has_builtin(__builtin_amdgcn_rcpf)
    return __builtin_amdgcn_rcpf(x);
#else
    return 1.0f / x;
#endif
}
__device__ __forceinline__ float sigm(float x) { return fastrcp(1.f + __expf(-x)); }
// tanh(x) = 1 - 2/(exp(2x)+1); saturates via exp overflow/underflow.
__device__ __forceinline__ float tanh_fast(float x) { return 1.f - 2.f * fastrcp(1.f + __expf(2.f * x)); }
// gate-interleaved permutation: g' = 4*h + gate  ->  original column gate*128 + h
__device__ __forceinline__ int orig_col(int gp) { return (gp & 3) * 128 + (gp >> 2); }

// ============================ X-projection GEMM ============================
// One WG per timestep t. X[t][b][g'] (f16, gate-interleaved, bias folded) =
// obs[t] @ Wi_perm + b_perm.  obs staged to LDS f16 in 4x[256][32] subtiles
// with in-subtile XOR swizzle; MFMA 16x16x32_f16, m=b, n=g', k=d.
__global__ __launch_bounds__(512, 2) void xproj_kernel(
    const float* __restrict__ obs, const float* __restrict__ Wi,
    const float* __restrict__ bvec, __half* __restrict__ X, int t0)
{
    const int t = t0 + blockIdx.x;
    const int tid = threadIdx.x, l = tid & 63, w = tid >> 6;
    __shared__ __align__(16) __half olds[4 * B_DIM * 32];  // 64 KB

    // B-frags (Wi_perm): wave owns n-tiles w*4..w*4+3; k = ks*32+8*(l>>4)+j
    f16x8 bf[4][4];
    float bias[4];
#pragma unroll
    for (int nt = 0; nt < 4; ++nt) {
        const int gp = (w * 4 + nt) * 16 + (l & 15);
        const int oc = orig_col(gp);
        bias[nt] = bvec[oc];
#pragma unroll
        for (int ks = 0; ks < 4; ++ks) {
            f16x8 f;
#pragma unroll
            for (int j = 0; j < 8; ++j)
                f[j] = (_Float16)Wi[(ks * 32 + 8 * (l >> 4) + j) * G_DIM + oc];
            bf[nt][ks] = f;
        }
    }

    // stage obs[t] -> f16 subtiled LDS: [ks][b][32] with 16B-block XOR ^(b&3)
    const float* ob = obs + (size_t)t * B_DIM * D_DIM;
#pragma unroll
    for (int u = 0; u < 16; ++u) {
        const int fi = u * 512 + tid;            // float4 index over 32768 floats
        float4 v = ((const float4*)ob)[fi];
        const int b = fi >> 5;                   // row
        const int d = (fi & 31) * 4;             // col 0..124 step 4
        const int ks = d >> 5, cb = (d & 31) >> 3, lo = d & 7;
        const int byte = ks * 16384 + b * 64 + 16 * (cb ^ (b & 3)) + lo * 2;
        *(__half2*)((char*)olds + byte)     = __floats2half2_rn(v.x, v.y);
        *(__half2*)((char*)olds + byte + 4) = __floats2half2_rn(v.z, v.w);
    }
    __syncthreads();

    __half* Xt = X + (size_t)blockIdx.x * B_DIM * G_DIM;
    for (int mt = 0; mt < 16; ++mt) {
        f16x8 af[4];
#pragma unroll
        for (int ks = 0; ks < 4; ++ks) {
            const int b = mt * 16 + (l & 15);
            const int byte = ks * 16384 + b * 64 + 16 * ((l >> 4) ^ (b & 3));
            af[ks] = *(const f16x8*)((const char*)olds + byte);
        }
        f32x4 acc[4];
#pragma unroll
        for (int nt = 0; nt < 4; ++nt)
            acc[nt][0] = acc[nt][1] = acc[nt][2] = acc[nt][3] = bias[nt];
#pragma unroll
        for (int ks = 0; ks < 4; ++ks)
#pragma unroll
            for (int nt = 0; nt < 4; ++nt)
                acc[nt] = __builtin_amdgcn_mfma_f32_16x16x32_f16(af[ks], bf[nt][ks], acc[nt], 0, 0, 0);
        // C/D: row(b) = mt*16+(l>>4)*4+r, col(g') = nt-tile base + (l&15)
#pragma unroll
        for (int nt = 0; nt < 4; ++nt) {
            const int gp = (w * 4 + nt) * 16 + (l & 15);
#pragma unroll
            for (int r = 0; r < 4; ++r) {
                const int b = mt * 16 + (l >> 4) * 4 + r;
                Xt[(size_t)b * G_DIM + gp] = __float2half(acc[nt][r]);
            }
        }
    }
}

// ================================ LSTM scan ================================
// 16 WGs x 512 thr; WG owns 16 batch rows. Per step: G^T[512,16] =
// Wh_perm^T @ h^T via 16 MFMA/wave (A static in regs), acc-init from X (f16).
// Lane's 4 acc slots per m-tile = {i,f,g,o} of one h (gate-interleave) for
// b = l&15. h in LDS 4x[16][32] f16 subtiles, XOR-swizzled, double-buffered;
// 1 barrier/step. done & X prefetched 2 steps ahead (2-phase reg rotation).
__global__ __launch_bounds__(512, 2) void scan_kernel(
    const __half* __restrict__ X, const int* __restrict__ done,
    const float* __restrict__ c0, const float* __restrict__ h0,
    const float* __restrict__ Wh, float* __restrict__ out,
    float* __restrict__ cst, float* __restrict__ hst,
    int t0, int slabT, int first, int last)
{
    const int tid = threadIdx.x, l = tid & 63, w = tid >> 6;
    const int bg = blockIdx.x * 16;
    const int bloc = l & 15, b = bg + bloc;
    __shared__ __align__(16) __half hlds[2][4 * 16 * 32];  // 2 x 4KB

    // A-frags: Wh_perm^T, m = gate' (m-tiles w*4..w*4+3), k = h_in
    f16x8 af[4][4];
#pragma unroll
    for (int i = 0; i < 4; ++i) {
        const int m = (w * 4 + i) * 16 + (l & 15);
        const int oc = orig_col(m);
#pragma unroll
        for (int ks = 0; ks < 4; ++ks) {
            f16x8 f;
#pragma unroll
            for (int j = 0; j < 8; ++j)
                f[j] = (_Float16)Wh[(ks * 32 + 8 * (l >> 4) + j) * G_DIM + oc];
            af[i][ks] = f;
        }
    }

    const float* csrc = first ? c0 : cst;
    const float* hsrc = first ? h0 : hst;
    float c[4], hl[4];
    int hout[4], wbyte[4];
#pragma unroll
    for (int i = 0; i < 4; ++i) {
        hout[i] = w * 16 + i * 4 + (l >> 4);
        c[i]  = csrc[(size_t)b * H_DIM + hout[i]];
        hl[i] = hsrc[(size_t)b * H_DIM + hout[i]];
        // h-write byte addr into subtiled-swizzled layout
        const int col = hout[i] & 31;
        wbyte[i] = (hout[i] >> 5) * 1024 + bloc * 64
                 + 16 * ((col >> 3) ^ (bloc & 3)) + (col & 7) * 2;
    }

    // h_lds[0] init from h-source, masked with done[t0]
    {
        const int bb = tid >> 5, hq = (tid & 31) * 4;
        const int dd = done[t0 * B_DIM + bg + bb];
        float v0 = hsrc[(size_t)(bg + bb) * H_DIM + hq + 0];
        float v1 = hsrc[(size_t)(bg + bb) * H_DIM + hq + 1];
        float v2 = hsrc[(size_t)(bg + bb) * H_DIM + hq + 2];
        float v3 = hsrc[(size_t)(bg + bb) * H_DIM + hq + 3];
        if (dd) { v0 = v1 = v2 = v3 = 0.f; }
        const int col = hq & 31;
        const int byte = (hq >> 5) * 1024 + bb * 64
                       + 16 * ((col >> 3) ^ (bb & 3)) + (col & 7) * 2;
        char* dst = (char*)&hlds[0][0] + byte;
        *(__half2*)dst       = __floats2half2_rn(v0, v1);
        *(__half2*)(dst + 4) = __floats2half2_rn(v2, v3);
    }

    // B-frag read addrs (loop-invariant; +4096 per parity)
    int bfa[4];
#pragma unroll
    for (int ks = 0; ks < 4; ++ks)
        bfa[ks] = ks * 1024 + bloc * 64 + 16 * ((l >> 4) ^ (bloc & 3));

    // done pipeline: dc0 = done[t0], dc1 = done[t0+1]
    int dc0 = done[t0 * B_DIM + b];
    int dc1 = done[(t0 + 1 < T_DIM ? t0 + 1 : T_DIM - 1) * B_DIM + b];

    // X pipeline: lane's 4 halfs per m-tile at g' base = hout*4
    const __half* Xb = X + (size_t)b * G_DIM;
    int xoff[4];
#pragma unroll
    for (int i = 0; i < 4; ++i) xoff[i] = hout[i] * 4;
    uint2 xA[4], xB[4];
#pragma unroll
    for (int i = 0; i < 4; ++i) {
        xA[i] = *(const uint2*)(Xb + xoff[i]);
        xB[i] = *(const uint2*)(Xb + (size_t)B_DIM * G_DIM + xoff[i]);
    }
    __syncthreads();

#define SSTEP(T_, XP_, DCc_, DCh_)                                             \
    {                                                                          \
        const int t = (T_);                                                    \
        const int par = (t - t0) & 1;                                          \
        f32x4 acc[4];                                                          \
        _Pragma("unroll")                                                      \
        for (int i = 0; i < 4; ++i) {                                          \
            const __half* xh = (const __half*)&XP_[i];                         \
            acc[i][0] = __half2float(xh[0]);                                   \
            acc[i][1] = __half2float(xh[1]);                                   \
            acc[i][2] = __half2float(xh[2]);                                   \
            acc[i][3] = __half2float(xh[3]);                                   \
        }                                                                      \
        { /* prefetch X, done for t+2 */                                       \
            const int tX = ((t + 2 - t0) < slabT ? (t + 2 - t0) : slabT - 1);  \
            _Pragma("unroll")                                                  \
            for (int i = 0; i < 4; ++i)                                        \
                XP_[i] = *(const uint2*)(Xb + (size_t)tX * B_DIM * G_DIM +     \
                                         xoff[i]);                             \
        }                                                                      \
        const bool mc = (DCc_ != 0);                                           \
        DCc_ = done[(t + 2 < T_DIM ? t + 2 : T_DIM - 1) * B_DIM + b];          \
        f16x8 bfr[4];                                                          \
        _Pragma("unroll")                                                      \
        for (int ks = 0; ks < 4; ++ks)                                         \
            bfr[ks] = *(const f16x8*)((const char*)&hlds[par][0] + bfa[ks]);   \
        _Pragma("unroll")                                                      \
        for (int i = 0; i < 4; ++i) c[i] = mc ? 0.f : c[i];                    \
        _Pragma("unroll")                                                      \
        for (int ks = 0; ks < 4; ++ks)                                         \
            _Pragma("unroll")                                                  \
            for (int i = 0; i < 4; ++i)                                        \
                acc[i] = __builtin_amdgcn_mfma_f32_16x16x32_f16(               \
                    af[i][ks], bfr[ks], acc[i], 0, 0, 0);                      \
        const bool mh = (DCh_ != 0);                                           \
        _Pragma("unroll")                                                      \
        for (int i = 0; i < 4; ++i) {                                          \
            const float ai  = sigm(acc[i][0]);                                 \
            const float afg = sigm(acc[i][1]);                                 \
            const float ag  = tanh_fast(acc[i][2]);                            \
            const float ao  = sigm(acc[i][3]);                                 \
            c[i] = afg * c[i] + ai * ag;                                       \
            const float hn = ao * tanh_fast(c[i]);                             \
            hl[i] = hn;                                                        \
            out[((size_t)t * B_DIM + b) * H_DIM + hout[i]] = hn;               \
            const float hw = mh ? 0.f : hn;                                    \
            *(__half*)((char*)&hlds[par ^ 1][0] + wbyte[i]) =                  \
                __float2half(hw);                                              \
        }                                                                      \
        __syncthreads();                                                       \
    }

#pragma unroll 1
    for (int tt = t0; tt < t0 + slabT; tt += 2) {
        SSTEP(tt + 0, xA, dc0, dc1)
        SSTEP(tt + 1, xB, dc1, dc0)
    }
#undef SSTEP

    // persist slab-boundary state; final slab also writes out carries
#pragma unroll
    for (int i = 0; i < 4; ++i) {
        cst[(size_t)b * H_DIM + hout[i]] = c[i];
        hst[(size_t)b * H_DIM + hout[i]] = hl[i];
    }
    if (last) {
        const size_t ybase = (size_t)T_DIM * B_DIM * H_DIM;
#pragma unroll
        for (int i = 0; i < 4; ++i) {
            out[ybase + (size_t)b * H_DIM + hout[i]] = c[i];
            out[ybase + (size_t)B_DIM * H_DIM + (size_t)b * H_DIM + hout[i]] = hl[i];
        }
    }
}

extern "C" void kernel_launch(void* const* d_in, const int* in_sizes, int n_in,
                              void* d_out, int out_size, void* d_ws, size_t ws_size,
                              hipStream_t stream) {
    const float* obs  = (const float*)d_in[0];
    const int*   done = (const int*)d_in[1];
    const float* c0   = (const float*)d_in[2];
    const float* h0   = (const float*)d_in[3];
    const float* Wi   = (const float*)d_in[4];
    const float* Wh   = (const float*)d_in[5];
    const float* bv   = (const float*)d_in[6];
    float* out = (float*)d_out;

    // slab the time axis so the X buffer fits d_ws (f16 X + 256KB state)
    int sT = T_DIM;
    while ((size_t)sT * B_DIM * G_DIM * 2 + 2 * B_DIM * H_DIM * 4 > ws_size && sT > 16)
        sT >>= 1;
    __half* X  = (__half*)d_ws;
    float* cst = (float*)((char*)d_ws + (size_t)sT * B_DIM * G_DIM * 2);
    float* hst = cst + B_DIM * H_DIM;

    for (int t0 = 0; t0 < T_DIM; t0 += sT) {
        xproj_kernel<<<dim3(sT), dim3(512), 0, stream>>>(obs, Wi, bv, X, t0);
        scan_kernel<<<dim3(16), dim3(512), 0, stream>>>(
            X, done, c0, h0, Wh, out, cst, hst,
            t0, sT, (t0 == 0) ? 1 : 0, (t0 + sT == T_DIM) ? 1 : 0);
    }
}